// Round 11
// baseline (311.407 us; speedup 1.0000x reference)
//
#include <hip/hip_runtime.h>

#define HW 4096
#define NCH 256
#define DIM 128
#define NPROTO 512

typedef __attribute__((ext_vector_type(4))) float f32x4;
typedef __attribute__((ext_vector_type(8))) short s16x8;
typedef __attribute__((ext_vector_type(4))) unsigned u32x4;

__device__ __forceinline__ unsigned short f2bf(float f) {
  union { float f; unsigned u; } v; v.f = f;
  unsigned r = v.u + 0x7fffu + ((v.u >> 16) & 1u);
  return (unsigned short)(r >> 16);
}

// packed f32x2 -> bf16x2 (low = lo, high = hi); no builtin on gfx950
__device__ __forceinline__ unsigned cvt_pk_bf16(float lo, float hi) {
  unsigned d;
  asm("v_cvt_pk_bf16_f32 %0, %1, %2" : "=v"(d) : "v"(lo), "v"(hi));
  return d;
}

// ---------------------------------------------------------------------------
// prep (verbatim from round 1, verified): P -> bf16 row-major [512][128] +
// pn2[512]; W -> bf16 row-major [128][256]
// ---------------------------------------------------------------------------
__global__ __launch_bounds__(256) void prep_kernel(const float* __restrict__ P,
                                                   const float* __restrict__ Wm,
                                                   unsigned short* __restrict__ Pbf,
                                                   unsigned short* __restrict__ Wbf,
                                                   float* __restrict__ pn2) {
  const int tid = threadIdx.x;
  const int b = blockIdx.x;
  if (b < 8) {
    const int n  = b * 64 + (tid >> 2);
    const int qt = tid & 3;
    const float* row = P + n * DIM + qt * 32;
    unsigned short* dst = Pbf + (size_t)n * DIM + qt * 32;
    float ssq = 0.f;
#pragma unroll
    for (int u = 0; u < 8; ++u) {
      f32x4 v = *(const f32x4*)(row + 4 * u);
      ssq += v.x * v.x + v.y * v.y + v.z * v.z + v.w * v.w;
      dst[4 * u + 0] = f2bf(v.x);
      dst[4 * u + 1] = f2bf(v.y);
      dst[4 * u + 2] = f2bf(v.z);
      dst[4 * u + 3] = f2bf(v.w);
    }
    ssq += __shfl_xor(ssq, 1);
    ssq += __shfl_xor(ssq, 2);
    if (qt == 0) pn2[n] = ssq;
  } else {
    const int idx = ((b - 8) * 256 + tid) * 16;
#pragma unroll
    for (int u = 0; u < 4; ++u) {
      f32x4 v = *(const f32x4*)(Wm + idx + 4 * u);
      unsigned short* d = Wbf + idx + 4 * u;
      d[0] = f2bf(v.x); d[1] = f2bf(v.y); d[2] = f2bf(v.z); d[3] = f2bf(v.w);
    }
  }
}

// ---------------------------------------------------------------------------
// fused v6: BARRIER-FREE, LDS-FREE single-wave dataflow.
// Why (r3-r10 evidence): every barrier-synced 8-wave schedule = 80+-3us with
// all pipes <26% and perfect serial block scaling (r7) -- barriers convoy
// all resident waves onto the same stall points. Remove all synchronization.
//
// Block = 2 independent waves (px-halves of a 32-px tile; paired only so the
// two 64B halves of each output 128B line are written together -- r9 lesson).
// Each wave: 16 px x 512 protos, everything in registers:
//  phase 1 (swapped): q^T[d][px] = W.x  -- A=W-frag direct from L2 (row=d),
//    B=x-frag direct from HBM (col=px; 8 f32 loads/lane, 64B segments), no
//    staging. acc1[8] = q^T tiles (row d=16t+4*l4+r, col px=l15).
//  transpose in-reg: cvt_pk + __shfl(bpermute) network -> qB[c][4] B-frags
//    (col=px, k=d). Lane-checked: qB[c][p] for lane l4 pulls pk[2c+(l4>>1)]
//    [p&1] from source lane l15+16*(2*(l4&1)+(p>>1)).
//  phase 2 (swapped): S^T = P.q^T -- A=P-frag from L2 row-major, acc2[32]
//    (row proto=16T+4*l4+r, col px=l15) = 128 VGPR.
//  softmax: rows are LANE-LOCAL (128 vals/lane) + shfl_xor(16,32) across
//    the 4 l4-groups. No LDS, no barriers anywhere.
//  stores: scalar f32, lanes l15 = 16 contiguous px = 64B segment/l4-group.
// ---------------------------------------------------------------------------
__global__ __launch_bounds__(128, 2) void fused_kernel(
    const float* __restrict__ x, const unsigned short* __restrict__ Wbf,
    const float* __restrict__ bias, const unsigned short* __restrict__ Pbf,
    const float* __restrict__ pn2, const float* __restrict__ gptr,
    float* __restrict__ out) {
  const int tid  = threadIdx.x;
  const int wv   = tid >> 6, lane = tid & 63;
  const int l15  = lane & 15, l4 = lane >> 4;
  const int p0   = blockIdx.x * 32;
  const int nimg = p0 >> 12;
  const int hw   = (p0 & 4095) + 16 * wv + l15;  // this lane's pixel column

  const float* xb = x + (size_t)nimg * NCH * HW + hw;

  // ---------------- phase 1: q^T = W . x (K = 256, 8 steps of 32) ----------
  f32x4 acc1[8];
#pragma unroll
  for (int t = 0; t < 8; ++t)
#pragma unroll
    for (int r = 0; r < 4; ++r) acc1[t][r] = 0.f;

#pragma unroll
  for (int s = 0; s < 8; ++s) {
    // x B-frag: col=px(l15), k=ch=32s+8*l4+j  -- direct from global
    float xr[8];
#pragma unroll
    for (int j = 0; j < 8; ++j)
      xr[j] = xb[(size_t)(32 * s + 8 * l4 + j) * HW];
    u32x4 bxu;
#pragma unroll
    for (int p = 0; p < 4; ++p)
      bxu[p] = cvt_pk_bf16(xr[2 * p], xr[2 * p + 1]);
    s16x8 bx = __builtin_bit_cast(s16x8, bxu);
#pragma unroll
    for (int t = 0; t < 8; ++t) {
      // W A-frag: row=d(l15), k=8*l4+j -- 16B/lane from L2-hot Wbf
      s16x8 aw = *(const s16x8*)(Wbf + (size_t)(16 * t + l15) * NCH + 32 * s + 8 * l4);
      acc1[t] = __builtin_amdgcn_mfma_f32_16x16x32_bf16(aw, bx, acc1[t], 0, 0, 0);
    }
  }

  // + bias (bias[d], d = 16t+4*l4+r; broadcast across l15)
#pragma unroll
  for (int t = 0; t < 8; ++t) {
    f32x4 bv = *(const f32x4*)(bias + 16 * t + 4 * l4);
#pragma unroll
    for (int r = 0; r < 4; ++r) acc1[t][r] += bv[r];
  }

  // ---------------- in-register transpose: acc1 -> qB (phase-2 B-frags) ----
  // pk[t][pr] = bf16x2 of (q^T[16t+4*l4+2pr][px], q^T[...+1][px])
  unsigned pk[8][2];
#pragma unroll
  for (int t = 0; t < 8; ++t)
#pragma unroll
    for (int pr = 0; pr < 2; ++pr)
      pk[t][pr] = cvt_pk_bf16(acc1[t][2 * pr], acc1[t][2 * pr + 1]);

  u32x4 qBu[4];
#pragma unroll
  for (int c = 0; c < 4; ++c)
#pragma unroll
    for (int p = 0; p < 4; ++p) {
      const int sl = l15 + 16 * (2 * (l4 & 1) + (p >> 1));
      unsigned va = (unsigned)__shfl((int)pk[2 * c + 0][p & 1], sl);
      unsigned vb = (unsigned)__shfl((int)pk[2 * c + 1][p & 1], sl);
      qBu[c][p] = (l4 >> 1) ? vb : va;
    }

  // ---------------- phase 2: S^T = P . q^T (512 protos, 32 tiles) ----------
  f32x4 acc2[32];
#pragma unroll
  for (int T = 0; T < 32; ++T)
#pragma unroll
    for (int r = 0; r < 4; ++r) acc2[T][r] = 0.f;

  const s16x8 qB0 = __builtin_bit_cast(s16x8, qBu[0]);
  const s16x8 qB1 = __builtin_bit_cast(s16x8, qBu[1]);
  const s16x8 qB2 = __builtin_bit_cast(s16x8, qBu[2]);
  const s16x8 qB3 = __builtin_bit_cast(s16x8, qBu[3]);

#pragma unroll
  for (int T = 0; T < 32; ++T) {
    const unsigned short* pr = Pbf + (size_t)(16 * T + l15) * DIM + 8 * l4;
    s16x8 a0 = *(const s16x8*)(pr + 0);
    s16x8 a1 = *(const s16x8*)(pr + 32);
    s16x8 a2 = *(const s16x8*)(pr + 64);
    s16x8 a3 = *(const s16x8*)(pr + 96);
    acc2[T] = __builtin_amdgcn_mfma_f32_16x16x32_bf16(a0, qB0, acc2[T], 0, 0, 0);
    acc2[T] = __builtin_amdgcn_mfma_f32_16x16x32_bf16(a1, qB1, acc2[T], 0, 0, 0);
    acc2[T] = __builtin_amdgcn_mfma_f32_16x16x32_bf16(a2, qB2, acc2[T], 0, 0, 0);
    acc2[T] = __builtin_amdgcn_mfma_f32_16x16x32_bf16(a3, qB3, acc2[T], 0, 0, 0);
  }

  // ---------------- softmax (lane-local rows + 2 shfl_xor) -----------------
  const float g2  = fabsf(gptr[0]) * 1.44269504088896340736f;
  const float tg2 = 2.f * g2;

  float m = -1e30f;
#pragma unroll
  for (int T = 0; T < 32; ++T) {
    f32x4 pv = *(const f32x4*)(pn2 + 16 * T + 4 * l4);  // proto = 16T+4*l4+r
#pragma unroll
    for (int r = 0; r < 4; ++r) {
      acc2[T][r] = fmaf(acc2[T][r], tg2, -g2 * pv[r]);
      m = fmaxf(m, acc2[T][r]);
    }
  }
  m = fmaxf(m, __shfl_xor(m, 16));
  m = fmaxf(m, __shfl_xor(m, 32));

  float ssum = 0.f;
#pragma unroll
  for (int T = 0; T < 32; ++T)
#pragma unroll
    for (int r = 0; r < 4; ++r) {
      float e = exp2f(acc2[T][r] - m);
      acc2[T][r] = e;
      ssum += e;
    }
  ssum += __shfl_xor(ssum, 16);
  ssum += __shfl_xor(ssum, 32);
  const float inv = 1.f / ssum;

  // ---------------- stores: lanes l15 = contiguous px (64B segments) -------
  float* ob = out + (size_t)nimg * NPROTO * HW + ((p0 & 4095) + 16 * wv + l15);
#pragma unroll
  for (int T = 0; T < 32; ++T)
#pragma unroll
    for (int r = 0; r < 4; ++r)
      ob[(size_t)(16 * T + 4 * l4 + r) * HW] = acc2[T][r] * inv;
}

extern "C" void kernel_launch(void* const* d_in, const int* in_sizes, int n_in,
                              void* d_out, int out_size, void* d_ws, size_t ws_size,
                              hipStream_t stream) {
  const float* x     = (const float*)d_in[0];
  const float* Wm    = (const float*)d_in[1];
  const float* bias  = (const float*)d_in[2];
  const float* prot  = (const float*)d_in[3];
  const float* gamma = (const float*)d_in[4];
  float* out = (float*)d_out;

  // workspace: Pbf row-major bf16 (128 KiB) | pn2 (2 KiB) | W bf16 (64 KiB)
  unsigned short* P_ws  = (unsigned short*)d_ws;
  float*          pn2_w = (float*)((char*)d_ws + 131072);
  unsigned short* W_ws  = (unsigned short*)((char*)d_ws + 131072 + 2048);

  prep_kernel<<<16, 256, 0, stream>>>(prot, Wm, P_ws, W_ws, pn2_w);
  fused_kernel<<<2048, 128, 0, stream>>>(x, W_ws, bias, P_ws, pn2_w, gamma, out);
}

// Round 12
// 268.940 us; speedup vs baseline: 1.1579x; 1.1579x over previous
//
#include <hip/hip_runtime.h>

#define HW 4096
#define NCH 256
#define DIM 128
#define NPROTO 512

typedef __attribute__((ext_vector_type(4))) float f32x4;
typedef __attribute__((ext_vector_type(8))) short s16x8;

__device__ __forceinline__ unsigned short f2bf(float f) {
  union { float f; unsigned u; } v; v.f = f;
  unsigned r = v.u + 0x7fffu + ((v.u >> 16) & 1u);
  return (unsigned short)(r >> 16);
}

// ---------------------------------------------------------------------------
// prep: P -> bf16 chunked Pr[ch][512][32] (+pn2); W -> bf16 row-major [128][256]
// ---------------------------------------------------------------------------
__global__ __launch_bounds__(256) void prep_kernel(const float* __restrict__ P,
                                                   const float* __restrict__ Wm,
                                                   unsigned short* __restrict__ Pr,
                                                   unsigned short* __restrict__ Wbf,
                                                   float* __restrict__ pn2) {
  const int tid = threadIdx.x;
  const int b = blockIdx.x;
  if (b < 8) {
    const int n  = b * 64 + (tid >> 2);
    const int qt = tid & 3;  // d-chunk 32*qt..
    const float* row = P + n * DIM + qt * 32;
    unsigned short* dst = Pr + ((size_t)qt * NPROTO + n) * 32;
    float ssq = 0.f;
#pragma unroll
    for (int u = 0; u < 8; ++u) {
      f32x4 v = *(const f32x4*)(row + 4 * u);
      ssq += v.x * v.x + v.y * v.y + v.z * v.z + v.w * v.w;
      dst[4 * u + 0] = f2bf(v.x);
      dst[4 * u + 1] = f2bf(v.y);
      dst[4 * u + 2] = f2bf(v.z);
      dst[4 * u + 3] = f2bf(v.w);
    }
    ssq += __shfl_xor(ssq, 1);
    ssq += __shfl_xor(ssq, 2);
    if (qt == 0) pn2[n] = ssq;
  } else {
    const int idx = ((b - 8) * 256 + tid) * 16;  // 8*256*16 = 32768 = 128*256
#pragma unroll
    for (int u = 0; u < 4; ++u) {
      f32x4 v = *(const f32x4*)(Wm + idx + 4 * u);
      unsigned short* d = Wbf + idx + 4 * u;
      d[0] = f2bf(v.x); d[1] = f2bf(v.y); d[2] = f2bf(v.z); d[3] = f2bf(v.w);
    }
  }
}

// ---------------------------------------------------------------------------
// fused v7: r10 per-half flow VERBATIM, but each block does TWO 32-px halves
// (1024 blocks x 512 thr). Mechanism (r7 probe: stores = ~31us/unit, drained
// SERIALLY at block exit; r9: long-lived dirty lines amplify -- so keep the
// window short):
//   - half-B's x prologue loads are issued BEFORE half-A's softmax+stores
//     (older than the stores in the in-order VMEM queue -> B's pack waits
//     only on them, not on the store drain)
//   - half-A's 32 store instrs drain under half-B's phase 1+2 (~4us compute)
//     instead of bursting at block exit and serializing with the next block
//   - wf/cj/bias/gamma hoisted once per block (halves the cold starts)
// Everything inside a half (pack/swizzle/barriers/bq dbuf/exp2 softmax/
// direct f32x4 stores) is byte-identical to r10 (proven correct, absmax ok).
// ---------------------------------------------------------------------------
__global__ __launch_bounds__(512, 4) void fused_kernel(
    const float* __restrict__ x, const unsigned short* __restrict__ Wbf,
    const float* __restrict__ bias, const unsigned short* __restrict__ Pr,
    const float* __restrict__ pn2, const float* __restrict__ gptr,
    float* __restrict__ out) {
  __shared__ __align__(16) char smem[18688];
  unsigned short* q_s = (unsigned short*)smem;  // [32][128] swizzled (8192)
  char* x_b = smem + 8192;                      // dbuf: 2 x (32 rows x 144B)
  float* red  = (float*)(smem + 17408);         // [8][32]
  float* rmx  = (float*)(smem + 18432);         // [32]
  float* rinv = (float*)(smem + 18560);         // [32]

  const int tid  = threadIdx.x;
  const int p0   = blockIdx.x * 64;  // 64-px tile, two 32-px halves
  const int nimg = p0 >> 12;
  const int hwb  = p0 & 4095;
  const int wave = tid >> 6, lane = tid & 63;
  const int l15 = lane & 15, l4 = lane >> 4;

  // ---- per-block prologue (once): W frags, bias, gamma, pn2, first xv ----
  const int dloc = 16 * wave + l15;
  s16x8 wf[8];
  {
    const unsigned short* wrow = Wbf + (size_t)dloc * NCH + 8 * l4;
#pragma unroll
    for (int k = 0; k < 8; ++k) wf[k] = *(const s16x8*)(wrow + 32 * k);
  }
  const float bv  = bias[dloc];
  const float g2  = fabsf(gptr[0]) * 1.44269504088896340736f;
  const float tg2 = 2.f * g2;
  float cj[4];
#pragma unroll
  for (int j = 0; j < 4; ++j) cj[j] = g2 * pn2[64 * wave + 16 * j + l15];

  const int f  = tid & 7;   // px quad: pixels 4f..4f+3
  const int cp = tid >> 3;  // channel pair 2cp,2cp+1 (stagers: tid<256)

  f32x4 xv[2][2];  // rolling 2-deep x prefetch (slot = K-step & 1)
  if (tid < 256) {
    const float* xb0 = x + (size_t)nimg * NCH * HW + hwb;
#pragma unroll
    for (int g = 0; g < 2; ++g) {
      xv[g][0] = *(const f32x4*)(xb0 + (size_t)(64 * g + 2 * cp + 0) * HW + 4 * f);
      xv[g][1] = *(const f32x4*)(xb0 + (size_t)(64 * g + 2 * cp + 1) * HW + 4 * f);
    }
  }
  __builtin_amdgcn_sched_barrier(0);

#pragma unroll
  for (int half = 0; half < 2; ++half) {
    const int hw0 = hwb + 32 * half;
    const float* xb = x + (size_t)nimg * NCH * HW + hw0;

    // ---------------- phase 1: q = x W^T ----------------
    f32x4 acc1[2];
#pragma unroll
    for (int i = 0; i < 2; ++i)
#pragma unroll
      for (int r = 0; r < 4; ++r) acc1[i][r] = 0.f;

#pragma unroll
    for (int it = 0; it < 4; ++it) {
      char* xbuf = x_b + (it & 1) * 4608;
      if (tid < 256) {
        // pack x(it): reg-dep wait drains the matching in-flight load
#pragma unroll
        for (int s = 0; s < 4; ++s) {
          const int row = 4 * f + s;
          unsigned pk = (unsigned)f2bf(xv[it & 1][0][s]) |
                        ((unsigned)f2bf(xv[it & 1][1][s]) << 16);
          *(unsigned*)(xbuf + row * 144 + ((4 * cp) ^ (((row >> 2) & 7) << 4))) = pk;
        }
        if (it + 2 < 4) {  // refill freed slot with this half's K-step it+2
          const int cc = 64 * (it + 2);
          xv[it & 1][0] = *(const f32x4*)(xb + (size_t)(cc + 2 * cp + 0) * HW + 4 * f);
          xv[it & 1][1] = *(const f32x4*)(xb + (size_t)(cc + 2 * cp + 1) * HW + 4 * f);
        }
      }
      __builtin_amdgcn_sched_barrier(0);
      asm volatile("s_waitcnt lgkmcnt(0)" ::: "memory");
      __builtin_amdgcn_s_barrier();
#pragma unroll
      for (int kc = 0; kc < 64; kc += 32) {
        const int ub = (kc >> 3) + l4;
        s16x8 a[2];
#pragma unroll
        for (int i = 0; i < 2; ++i) {
          const int row = 16 * i + l15;
          a[i] = *(const s16x8*)(xbuf + row * 144 + 16 * (ub ^ ((row >> 2) & 7)));
        }
#pragma unroll
        for (int i = 0; i < 2; ++i)
          acc1[i] = __builtin_amdgcn_mfma_f32_16x16x32_bf16(a[i], wf[2 * it + (kc >> 5)],
                                                            acc1[i], 0, 0, 0);
      }
    }

    // ---------------- phase 1.5: q + bias -> q_s (swizzled bf16) ----------
    {
      const int u = dloc >> 3, d7 = dloc & 7;
#pragma unroll
      for (int i = 0; i < 2; ++i) {
        const int pxb = 16 * i + 4 * l4;
#pragma unroll
        for (int r = 0; r < 4; ++r) {
          const int px = pxb + r;
          q_s[px * 128 + ((u ^ (px & 7)) << 3) + d7] = f2bf(acc1[i][r] + bv);
        }
      }
    }

    // ---------------- phase 2: attn, bq double-buffered from L2 ----------
    f32x4 acc[2][4];
#pragma unroll
    for (int i = 0; i < 2; ++i)
#pragma unroll
      for (int j = 0; j < 4; ++j)
#pragma unroll
        for (int r = 0; r < 4; ++r) acc[i][j][r] = 0.f;

    s16x8 bqA[4], bqB[4];
#pragma unroll
    for (int j = 0; j < 4; ++j)
      bqA[j] = *(const s16x8*)(Pr + (size_t)(0 * NPROTO + 64 * wave + 16 * j + l15) * 32 + 8 * l4);
#pragma unroll
    for (int j = 0; j < 4; ++j)
      bqB[j] = *(const s16x8*)(Pr + (size_t)(1 * NPROTO + 64 * wave + 16 * j + l15) * 32 + 8 * l4);
    asm volatile("s_waitcnt lgkmcnt(0)" ::: "memory");
    __builtin_amdgcn_s_barrier();  // q_s visible; bq loads stay in flight

#define DO_CHUNK(CH, BQ)                                                        \
    {                                                                           \
      s16x8 afr[2];                                                             \
      _Pragma("unroll") for (int i = 0; i < 2; ++i) {                           \
        const int px = 16 * i + l15;                                            \
        afr[i] = *(const s16x8*)&q_s[px * 128 + (((4 * (CH) + l4) ^ (px & 7)) << 3)]; \
      }                                                                         \
      _Pragma("unroll") for (int j = 0; j < 4; ++j)                             \
        _Pragma("unroll") for (int i = 0; i < 2; ++i)                           \
          acc[i][j] = __builtin_amdgcn_mfma_f32_16x16x32_bf16(afr[i], BQ[j], acc[i][j], 0, 0, 0); \
    }

    DO_CHUNK(0, bqA);
#pragma unroll
    for (int j = 0; j < 4; ++j)
      bqA[j] = *(const s16x8*)(Pr + (size_t)(2 * NPROTO + 64 * wave + 16 * j + l15) * 32 + 8 * l4);
    DO_CHUNK(1, bqB);
#pragma unroll
    for (int j = 0; j < 4; ++j)
      bqB[j] = *(const s16x8*)(Pr + (size_t)(3 * NPROTO + 64 * wave + 16 * j + l15) * 32 + 8 * l4);
    DO_CHUNK(2, bqA);
    DO_CHUNK(3, bqB);
#undef DO_CHUNK

    // issue next half's first 2 x K-steps NOW -- BEFORE this half's stores,
    // so they sit OLDER in the in-order VMEM queue (B's pack won't wait on
    // the store drain), and their latency hides under the softmax VALU work
    if (half == 0 && tid < 256) {
      const float* xbn = xb + 32;
#pragma unroll
      for (int g = 0; g < 2; ++g) {
        xv[g][0] = *(const f32x4*)(xbn + (size_t)(64 * g + 2 * cp + 0) * HW + 4 * f);
        xv[g][1] = *(const f32x4*)(xbn + (size_t)(64 * g + 2 * cp + 1) * HW + 4 * f);
      }
    }
    __builtin_amdgcn_sched_barrier(0);

    // ---------------- softmax over 512 protos (exp2 domain) --------------
#pragma unroll
    for (int i = 0; i < 2; ++i)
#pragma unroll
      for (int r = 0; r < 4; ++r) {
        float m = -1e30f;
#pragma unroll
        for (int j = 0; j < 4; ++j) {
          float lv = fmaf(acc[i][j][r], tg2, -cj[j]);
          acc[i][j][r] = lv;
          m = fmaxf(m, lv);
        }
#pragma unroll
        for (int s = 1; s < 16; s <<= 1) m = fmaxf(m, __shfl_xor(m, s));
        if (l15 == 0) red[wave * 32 + 16 * i + 4 * l4 + r] = m;
      }
    __syncthreads();
    if (tid < 32) {
      float M = red[tid];
#pragma unroll
      for (int w = 1; w < 8; ++w) M = fmaxf(M, red[w * 32 + tid]);
      rmx[tid] = M;
    }
    __syncthreads();

#pragma unroll
    for (int i = 0; i < 2; ++i) {
      const f32x4 Mi = *(const f32x4*)&rmx[16 * i + 4 * l4];
#pragma unroll
      for (int r = 0; r < 4; ++r) {
        float s = 0.f;
#pragma unroll
        for (int j = 0; j < 4; ++j) {
          float e = exp2f(acc[i][j][r] - Mi[r]);
          acc[i][j][r] = e;
          s += e;
        }
#pragma unroll
        for (int t = 1; t < 16; t <<= 1) s += __shfl_xor(s, t);
        if (l15 == 0) red[wave * 32 + 16 * i + 4 * l4 + r] = s;
      }
    }
    __syncthreads();
    if (tid < 32) {
      float S = 0.f;
#pragma unroll
      for (int w = 0; w < 8; ++w) S += red[w * 32 + tid];
      rinv[tid] = 1.f / S;
    }
    __syncthreads();

    // ---------------- stores: issued, NOT waited (drain under next half) --
    float* ob = out + (size_t)nimg * NPROTO * HW + hw0;
#pragma unroll
    for (int i = 0; i < 2; ++i) {
      const f32x4 iv = *(const f32x4*)&rinv[16 * i + 4 * l4];
      const int px = 16 * i + 4 * l4;
#pragma unroll
      for (int j = 0; j < 4; ++j) {
        const int k = 64 * wave + 16 * j + l15;
        f32x4 o = acc[i][j] * iv;
        *(f32x4*)(ob + (size_t)k * HW + px) = o;
      }
    }
  }
}

extern "C" void kernel_launch(void* const* d_in, const int* in_sizes, int n_in,
                              void* d_out, int out_size, void* d_ws, size_t ws_size,
                              hipStream_t stream) {
  const float* x     = (const float*)d_in[0];
  const float* Wm    = (const float*)d_in[1];
  const float* bias  = (const float*)d_in[2];
  const float* prot  = (const float*)d_in[3];
  const float* gamma = (const float*)d_in[4];
  float* out = (float*)d_out;

  // workspace: Pr chunked bf16 (128 KiB) | pn2 (2 KiB) | W bf16 (64 KiB)
  unsigned short* Pr_w  = (unsigned short*)d_ws;
  float*          pn2_w = (float*)((char*)d_ws + 131072);
  unsigned short* W_ws  = (unsigned short*)((char*)d_ws + 131072 + 2048);

  prep_kernel<<<16, 256, 0, stream>>>(prot, Wm, Pr_w, W_ws, pn2_w);
  fused_kernel<<<1024, 512, 0, stream>>>(x, W_ws, bias, Pr_w, pn2_w, gamma, out);
}